// Round 1
// baseline (2423.095 us; speedup 1.0000x reference)
//
#include <hip/hip_runtime.h>

// Elman RNN on MI355X. B=64, T=2048, D=H=256.
// Kernel 1: px = xs @ W_ih + b_hh  (f16 MFMA, fp32 out) written into ys region.
// Kernel 2: sequential scan, 4 blocks x 16 rows, 4 waves x 64 cols each.
//           W_hh resident in 128 VGPRs/wave; h round-trips through XOR-swizzled
//           LDS each step. All addressing hoisted: per-thread offsets computed
//           once, uniform base pointers advance by scalar adds, t-loop unrolled
//           x2 so LDS buffer select is an immediate. ys overwritten in place
//           (px[b,t] read one step before h[b,t] written).

typedef _Float16 half8 __attribute__((ext_vector_type(8)));
typedef float floatx4 __attribute__((ext_vector_type(4)));
typedef float f32x4 __attribute__((ext_vector_type(4)));

constexpr int Bb = 64, Tt = 2048, Dd = 256, Hh = 256;

// LDS address for h[row][col], row in [0,16), col in [0,256), f16 elements.
// 16B blocks along col; XOR-swizzle block index with (row&7) so that
// A-fragment ds_read_b128 (fixed col-block per lane, row=lane&15) is
// bank-conflict-free; epilogue 2B h-writes are ~2-way (free tier).
__device__ __forceinline__ int lds_addr(int row, int col) {
    return row * 512 + ((((col >> 3) ^ (row & 7)) & 31) << 4) + ((col & 7) << 1);
}

__device__ __forceinline__ float fast_tanh(float x) {
    // tanh(x) = 1 - 2/(exp2(x*2*log2(e)) + 1); exact at +/-inf, ~1e-6 abs err.
    float e = __builtin_amdgcn_exp2f(x * 2.885390081777927f);
    float r = __builtin_amdgcn_rcpf(e + 1.0f);
    return __builtin_fmaf(-2.0f, r, 1.0f);
}

// ---------------------------------------------------------------------------
// Kernel 1: px[b*T+t][n] = sum_k xs[b*T+t][k] * W_ih[k][n] + b_hh[n]
// Block: 256 thr (4 waves). Wave w owns cols [64w, 64w+64) (4 n-tiles),
// W_ih fragments register-resident (128 VGPRs). Block processes 8 row-tiles
// of 16; all 4 waves read the same 16 xs rows (L1 absorbs the reuse).
// (unchanged this round — isolating the scan rewrite)
// ---------------------------------------------------------------------------
__global__ __launch_bounds__(256, 2) void px_gemm(const float* __restrict__ xs,
                                                  const float* __restrict__ Wih,
                                                  const float* __restrict__ bhh,
                                                  float* __restrict__ px) {
    const int lane = threadIdx.x & 63;
    const int w = threadIdx.x >> 6;   // 0..3
    const int q = lane >> 4;          // 0..3
    const int m = lane & 15;

    // B fragments: B[k][n], n = lane&15 + tile base, k = 8*q + j + 32*c.
    half8 bf[4][8];
#pragma unroll
    for (int tt = 0; tt < 4; ++tt) {
        const int n = 64 * w + 16 * tt + m;
#pragma unroll
        for (int c = 0; c < 8; ++c) {
            half8 f;
#pragma unroll
            for (int j = 0; j < 8; ++j)
                f[j] = (_Float16)Wih[(32 * c + 8 * q + j) * Hh + n];
            bf[tt][c] = f;
        }
    }
    float bias[4];
#pragma unroll
    for (int tt = 0; tt < 4; ++tt) bias[tt] = bhh[64 * w + 16 * tt + m];

    for (int i = 0; i < 8; ++i) {
        const int tau = blockIdx.x * 8 + i;             // 16-row tile index
        const float* arow = xs + (size_t)(tau * 16 + m) * Dd;
        half8 af[8];
#pragma unroll
        for (int c = 0; c < 8; ++c) {
            f32x4 lo = *(const f32x4*)(arow + 32 * c + 8 * q);
            f32x4 hi = *(const f32x4*)(arow + 32 * c + 8 * q + 4);
            half8 f;
            f[0] = (_Float16)lo[0]; f[1] = (_Float16)lo[1];
            f[2] = (_Float16)lo[2]; f[3] = (_Float16)lo[3];
            f[4] = (_Float16)hi[0]; f[5] = (_Float16)hi[1];
            f[6] = (_Float16)hi[2]; f[7] = (_Float16)hi[3];
            af[c] = f;
        }
        floatx4 acc[4];
#pragma unroll
        for (int tt = 0; tt < 4; ++tt) {
            acc[tt][0] = bias[tt]; acc[tt][1] = bias[tt];
            acc[tt][2] = bias[tt]; acc[tt][3] = bias[tt];
        }
#pragma unroll
        for (int c = 0; c < 8; ++c)
#pragma unroll
            for (int tt = 0; tt < 4; ++tt)
                acc[tt] = __builtin_amdgcn_mfma_f32_16x16x32_f16(af[c], bf[tt][c], acc[tt], 0, 0, 0);
        // C layout: row = 4*q + r, col = 16*tile + (lane&15)
#pragma unroll
        for (int tt = 0; tt < 4; ++tt)
#pragma unroll
            for (int r = 0; r < 4; ++r)
                px[(size_t)(tau * 16 + 4 * q + r) * Hh + 64 * w + 16 * tt + m] = acc[tt][r];
    }
}

// ---------------------------------------------------------------------------
// Kernel 2: scan. Grid = 4 blocks (16 batch rows each), 256 thr = 4 waves
// (1 wave/SIMD). Wave w owns cols [64w, 64w+64) (4 n-tiles); W_hh fragments
// in 128 VGPRs. Per step: prefetch px[t+1] via fixed VGPR offsets + scalar
// base bump, 8x ds_read_b128 A frags (precomputed swizzled addrs, buffer
// select folded to offset:8192 immediate via x2 unroll), 32 MFMA k-major
// (4 chains, dep distance 4), tanh, dword store + 2B LDS write. 1 barrier/step.
// ---------------------------------------------------------------------------
__global__ __launch_bounds__(256, 1) void rnn_scan(const float* __restrict__ c0,
                                                   const float* __restrict__ Whh,
                                                   float* __restrict__ hfin,
                                                   float* __restrict__ ys) {
    __shared__ alignas(16) unsigned char hb[2][8192];
    const int g = blockIdx.x;         // row group: rows [16g, 16g+16)
    const int lane = threadIdx.x & 63;
    const int w = threadIdx.x >> 6;   // 0..3
    const int q = lane >> 4;
    const int m = lane & 15;

    // W_hh B fragments (one-time, scattered fp32 loads + cvt). 128 VGPRs.
    half8 bf[4][8];
#pragma unroll
    for (int tt = 0; tt < 4; ++tt) {
        const int n = 64 * w + 16 * tt + m;
#pragma unroll
        for (int c = 0; c < 8; ++c) {
            half8 f;
#pragma unroll
            for (int j = 0; j < 8; ++j)
                f[j] = (_Float16)Whh[(32 * c + 8 * q + j) * Hh + n];
            bf[tt][c] = f;
        }
    }

    // h_0 = c rows -> LDS buffer 0 (f16, swizzled).
    for (int i = threadIdx.x; i < 16 * 256; i += 256) {
        const int row = i >> 8, col = i & 255;
        *(_Float16*)&hb[0][lds_addr(row, col)] = (_Float16)c0[(16 * g + row) * Hh + col];
    }

    // Per-thread byte offsets into ys (row-major [B,T,H], row term t added via
    // the uniform base pointer). k = 4*tt + r. Max ~132 MB, fits unsigned.
    unsigned boff[16];
#pragma unroll
    for (int tt = 0; tt < 4; ++tt)
#pragma unroll
        for (int r = 0; r < 4; ++r)
            boff[4 * tt + r] =
                (unsigned)(((16 * g + 4 * q + r) * Tt) * Hh + 64 * w + 16 * tt + m) * 4u;

    // A-fragment LDS read addrs (row=m, col block 4c+q, swizzled), buffer 0.
    int ard[8];
#pragma unroll
    for (int c = 0; c < 8; ++c)
        ard[c] = m * 512 + ((((4 * c + q) ^ (m & 7)) & 31) << 4);

    // h write LDS addrs, buffer-relative.
    int wad[16];
#pragma unroll
    for (int tt = 0; tt < 4; ++tt)
#pragma unroll
        for (int r = 0; r < 4; ++r)
            wad[4 * tt + r] = lds_addr(4 * q + r, 64 * w + 16 * tt + m);

    const char* pxp = (const char*)ys;                              // prefetch base
    const char* pxlast = (const char*)ys + (size_t)(Tt - 1) * Hh * 4;
    char* yst = (char*)ys;                                          // store base

    // Prime px for t=0.
    float pxA[16], pxB[16];
#pragma unroll
    for (int k = 0; k < 16; ++k) pxA[k] = *(const float*)(pxp + boff[k]);
    pxp += Hh * 4;

    __syncthreads();

#define RNN_STEP(P, PXC, PXN, LASTCHK, TCUR)                                   \
    {                                                                          \
        const char* pf = (pxp > pxlast) ? pxlast : pxp; /* uniform clamp */    \
        _Pragma("unroll") for (int k2 = 0; k2 < 16; ++k2)                      \
            PXN[k2] = *(const float*)(pf + boff[k2]);                          \
        pxp += Hh * 4;                                                         \
        half8 af[8];                                                           \
        _Pragma("unroll") for (int c2 = 0; c2 < 8; ++c2)                       \
            af[c2] = *(const half8*)&hb[(P)][ard[c2]];                         \
        floatx4 acc[4];                                                        \
        _Pragma("unroll") for (int u2 = 0; u2 < 4; ++u2) {                     \
            acc[u2][0] = PXC[4 * u2 + 0]; acc[u2][1] = PXC[4 * u2 + 1];        \
            acc[u2][2] = PXC[4 * u2 + 2]; acc[u2][3] = PXC[4 * u2 + 3];        \
        }                                                                      \
        /* k-major: 4 independent acc chains, dep distance 4 */                \
        _Pragma("unroll") for (int c2 = 0; c2 < 8; ++c2)                       \
            _Pragma("unroll") for (int u2 = 0; u2 < 4; ++u2)                   \
                acc[u2] = __builtin_amdgcn_mfma_f32_16x16x32_f16(              \
                    af[c2], bf[u2][c2], acc[u2], 0, 0, 0);                     \
        _Pragma("unroll") for (int u2 = 0; u2 < 4; ++u2)                       \
            _Pragma("unroll") for (int r2 = 0; r2 < 4; ++r2) {                 \
                const float hv = fast_tanh(acc[u2][r2]);                       \
                *(float*)(yst + boff[4 * u2 + r2]) = hv;                       \
                *(_Float16*)&hb[(P) ^ 1][wad[4 * u2 + r2]] = (_Float16)hv;     \
                if ((LASTCHK) && (TCUR) == Tt - 1)                             \
                    hfin[(16 * g + 4 * q + r2) * Hh + 64 * w + 16 * u2 + m] = hv; \
            }                                                                  \
        yst += Hh * 4;                                                         \
        __syncthreads();                                                       \
    }

    for (int t = 0; t < Tt; t += 2) {
        RNN_STEP(0, pxA, pxB, 0, t)
        RNN_STEP(1, pxB, pxA, 1, t + 1)
    }
#undef RNN_STEP
}

extern "C" void kernel_launch(void* const* d_in, const int* in_sizes, int n_in,
                              void* d_out, int out_size, void* d_ws, size_t ws_size,
                              hipStream_t stream) {
    const float* c0  = (const float*)d_in[0];  // [B,H]
    const float* xs  = (const float*)d_in[1];  // [B,T,D]
    const float* Wih = (const float*)d_in[2];  // [D,H]
    const float* Whh = (const float*)d_in[3];  // [H,H]
    const float* bhh = (const float*)d_in[4];  // [H]
    float* out = (float*)d_out;
    float* hfin = out;                 // [B,H]
    float* ys = out + Bb * Hh;         // [B,T,H] — also holds px between kernels

    // 1024 blocks * 8 tiles * 16 rows = 131072 = B*T rows.
    px_gemm<<<1024, 256, 0, stream>>>(xs, Wih, bhh, ys);
    // 4 blocks * 16 rows = 64 batch chains.
    rnn_scan<<<Bb / 16, 256, 0, stream>>>(c0, Whh, hfin, ys);
}

// Round 2
// 1723.155 us; speedup vs baseline: 1.4062x; 1.4062x over previous
//
#include <hip/hip_runtime.h>

// Elman RNN on MI355X. B=64, T=2048, D=H=256.
// Kernel 1: px = xs @ W_ih + b_hh  (f16 MFMA, fp32 out) written into ys region.
// Kernel 2: sequential scan, 4 blocks x 16 rows, 8 waves x 32 cols each
//           (2 waves/SIMD for latency hiding). W_hh resident in 64 VGPRs/wave;
//           h round-trips through XOR-swizzled LDS each step. All addressing
//           hoisted (per-thread offsets once, uniform scalar base bumps,
//           x2 unroll folds LDS ping-pong into an immediate). Barrier is raw
//           lgkmcnt(0)+s_barrier so px prefetch/ys stores stay in flight
//           across steps (no vmcnt drain). ys overwritten in place
//           (px[b,t] read one step before h[b,t] written, same thread).

typedef _Float16 half8 __attribute__((ext_vector_type(8)));
typedef float floatx4 __attribute__((ext_vector_type(4)));
typedef float f32x4 __attribute__((ext_vector_type(4)));

constexpr int Bb = 64, Tt = 2048, Dd = 256, Hh = 256;

// LDS address for h[row][col], row in [0,16), col in [0,256), f16 elements.
// 16B blocks along col; XOR-swizzle block index with (row&7) so that
// A-fragment ds_read_b128 (fixed col-block per lane, row=lane&15) is
// bank-conflict-free; epilogue 2B h-writes are ~2-way (free tier).
__device__ __forceinline__ int lds_addr(int row, int col) {
    return row * 512 + ((((col >> 3) ^ (row & 7)) & 31) << 4) + ((col & 7) << 1);
}

__device__ __forceinline__ float fast_tanh(float x) {
    // tanh(x) = 1 - 2/(exp2(x*2*log2(e)) + 1); exact at +/-inf, ~1e-6 abs err.
    float e = __builtin_amdgcn_exp2f(x * 2.885390081777927f);
    float r = __builtin_amdgcn_rcpf(e + 1.0f);
    return __builtin_fmaf(-2.0f, r, 1.0f);
}

// LDS-only barrier: makes this wave's ds ops complete, then syncs. Does NOT
// drain vmcnt, so global loads/stores issued before it stay in flight.
// Memory clobber keeps all memory ops on their side of the barrier.
#define LDS_BARRIER() asm volatile("s_waitcnt lgkmcnt(0)\n\ts_barrier" ::: "memory")

// ---------------------------------------------------------------------------
// Kernel 1: px[b*T+t][n] = sum_k xs[b*T+t][k] * W_ih[k][n] + b_hh[n]
// (unchanged — isolating the scan change this round)
// ---------------------------------------------------------------------------
__global__ __launch_bounds__(256, 2) void px_gemm(const float* __restrict__ xs,
                                                  const float* __restrict__ Wih,
                                                  const float* __restrict__ bhh,
                                                  float* __restrict__ px) {
    const int lane = threadIdx.x & 63;
    const int w = threadIdx.x >> 6;   // 0..3
    const int q = lane >> 4;          // 0..3
    const int m = lane & 15;

    // B fragments: B[k][n], n = lane&15 + tile base, k = 8*q + j + 32*c.
    half8 bf[4][8];
#pragma unroll
    for (int tt = 0; tt < 4; ++tt) {
        const int n = 64 * w + 16 * tt + m;
#pragma unroll
        for (int c = 0; c < 8; ++c) {
            half8 f;
#pragma unroll
            for (int j = 0; j < 8; ++j)
                f[j] = (_Float16)Wih[(32 * c + 8 * q + j) * Hh + n];
            bf[tt][c] = f;
        }
    }
    float bias[4];
#pragma unroll
    for (int tt = 0; tt < 4; ++tt) bias[tt] = bhh[64 * w + 16 * tt + m];

    for (int i = 0; i < 8; ++i) {
        const int tau = blockIdx.x * 8 + i;             // 16-row tile index
        const float* arow = xs + (size_t)(tau * 16 + m) * Dd;
        half8 af[8];
#pragma unroll
        for (int c = 0; c < 8; ++c) {
            f32x4 lo = *(const f32x4*)(arow + 32 * c + 8 * q);
            f32x4 hi = *(const f32x4*)(arow + 32 * c + 8 * q + 4);
            half8 f;
            f[0] = (_Float16)lo[0]; f[1] = (_Float16)lo[1];
            f[2] = (_Float16)lo[2]; f[3] = (_Float16)lo[3];
            f[4] = (_Float16)hi[0]; f[5] = (_Float16)hi[1];
            f[6] = (_Float16)hi[2]; f[7] = (_Float16)hi[3];
            af[c] = f;
        }
        floatx4 acc[4];
#pragma unroll
        for (int tt = 0; tt < 4; ++tt) {
            acc[tt][0] = bias[tt]; acc[tt][1] = bias[tt];
            acc[tt][2] = bias[tt]; acc[tt][3] = bias[tt];
        }
#pragma unroll
        for (int c = 0; c < 8; ++c)
#pragma unroll
            for (int tt = 0; tt < 4; ++tt)
                acc[tt] = __builtin_amdgcn_mfma_f32_16x16x32_f16(af[c], bf[tt][c], acc[tt], 0, 0, 0);
        // C layout: row = 4*q + r, col = 16*tile + (lane&15)
#pragma unroll
        for (int tt = 0; tt < 4; ++tt)
#pragma unroll
            for (int r = 0; r < 4; ++r)
                px[(size_t)(tau * 16 + 4 * q + r) * Hh + 64 * w + 16 * tt + m] = acc[tt][r];
    }
}

// ---------------------------------------------------------------------------
// Kernel 2: scan. Grid = 4 blocks (16 batch rows each), 512 thr = 8 waves
// (2 waves/SIMD). Wave w owns cols [32w, 32w+32) (2 n-tiles); W_hh fragments
// in 64 VGPRs. Per step: 8x ds_read_b128 A frags (precomputed swizzled addrs,
// ping-pong folded to +8192 immediate via x2 unroll), prefetch px[t+1]
// (fixed VGPR offsets + scalar base bump, rides across the barrier),
// 16 MFMA (2 chains), tanh, dword store + 2B LDS write, LDS-only barrier.
// ---------------------------------------------------------------------------
__global__ __launch_bounds__(512, 2) void rnn_scan(const float* __restrict__ c0,
                                                   const float* __restrict__ Whh,
                                                   float* __restrict__ hfin,
                                                   float* __restrict__ ys) {
    __shared__ alignas(16) unsigned char hb[2][8192];
    const int g = blockIdx.x;         // row group: rows [16g, 16g+16)
    const int lane = threadIdx.x & 63;
    const int w = threadIdx.x >> 6;   // 0..7
    const int q = lane >> 4;
    const int m = lane & 15;

    // W_hh B fragments (one-time, scattered fp32 loads + cvt). 64 VGPRs.
    half8 bf[2][8];
#pragma unroll
    for (int tt = 0; tt < 2; ++tt) {
        const int n = 32 * w + 16 * tt + m;
#pragma unroll
        for (int c = 0; c < 8; ++c) {
            half8 f;
#pragma unroll
            for (int j = 0; j < 8; ++j)
                f[j] = (_Float16)Whh[(32 * c + 8 * q + j) * Hh + n];
            bf[tt][c] = f;
        }
    }

    // h_0 = c rows -> LDS buffer 0 (f16, swizzled).
    for (int i = threadIdx.x; i < 16 * 256; i += 512) {
        const int row = i >> 8, col = i & 255;
        *(_Float16*)&hb[0][lds_addr(row, col)] = (_Float16)c0[(16 * g + row) * Hh + col];
    }

    // Per-thread byte offsets into ys (row-major [B,T,H]; the t term advances
    // via uniform base pointers). k = 4*tt + r. Max ~132 MB, fits unsigned.
    unsigned boff[8];
#pragma unroll
    for (int tt = 0; tt < 2; ++tt)
#pragma unroll
        for (int r = 0; r < 4; ++r)
            boff[4 * tt + r] =
                (unsigned)(((16 * g + 4 * q + r) * Tt) * Hh + 32 * w + 16 * tt + m) * 4u;

    // A-fragment LDS read addrs (row=m, col block 4c+q, swizzled), buffer 0.
    int ard[8];
#pragma unroll
    for (int c = 0; c < 8; ++c)
        ard[c] = m * 512 + ((((4 * c + q) ^ (m & 7)) & 31) << 4);

    // h write LDS addrs, buffer-relative.
    int wad[8];
#pragma unroll
    for (int tt = 0; tt < 2; ++tt)
#pragma unroll
        for (int r = 0; r < 4; ++r)
            wad[4 * tt + r] = lds_addr(4 * q + r, 32 * w + 16 * tt + m);

    const char* pxp = (const char*)ys;                              // prefetch base
    const char* pxlast = (const char*)ys + (size_t)(Tt - 1) * Hh * 4;
    char* yst = (char*)ys;                                          // store base

    // Prime px for t=0 (directly into the MFMA C layout: floatx4 per tile).
    floatx4 pxA[2], pxB[2];
#pragma unroll
    for (int k = 0; k < 8; ++k) pxA[k >> 2][k & 3] = *(const float*)(pxp + boff[k]);
    pxp += Hh * 4;

    __syncthreads();

#define RNN_STEP(P, PXC, PXN, LASTCHK, TCUR)                                   \
    {                                                                          \
        /* A fragments first: MFMA needs them ASAP. */                         \
        half8 af[8];                                                           \
        _Pragma("unroll") for (int c2 = 0; c2 < 8; ++c2)                       \
            af[c2] = *(const half8*)&hb[(P)][ard[c2]];                         \
        /* Next step's px: issued now, consumed after the next barrier. */     \
        const char* pf = (pxp > pxlast) ? pxlast : pxp; /* uniform clamp */    \
        _Pragma("unroll") for (int k2 = 0; k2 < 8; ++k2)                       \
            PXN[k2 >> 2][k2 & 3] = *(const float*)(pf + boff[k2]);             \
        pxp += Hh * 4;                                                         \
        floatx4 acc0 = PXC[0], acc1 = PXC[1];                                  \
        _Pragma("unroll") for (int c2 = 0; c2 < 8; ++c2)                       \
            acc0 = __builtin_amdgcn_mfma_f32_16x16x32_f16(af[c2], bf[0][c2],   \
                                                          acc0, 0, 0, 0);      \
        _Pragma("unroll") for (int c2 = 0; c2 < 8; ++c2)                       \
            acc1 = __builtin_amdgcn_mfma_f32_16x16x32_f16(af[c2], bf[1][c2],   \
                                                          acc1, 0, 0, 0);      \
        _Pragma("unroll") for (int r2 = 0; r2 < 4; ++r2) {                     \
            const float hv = fast_tanh(acc0[r2]);                              \
            *(float*)(yst + boff[r2]) = hv;                                    \
            *(_Float16*)&hb[(P) ^ 1][wad[r2]] = (_Float16)hv;                  \
        }                                                                      \
        _Pragma("unroll") for (int r2 = 0; r2 < 4; ++r2) {                     \
            const float hv = fast_tanh(acc1[r2]);                              \
            *(float*)(yst + boff[4 + r2]) = hv;                                \
            *(_Float16*)&hb[(P) ^ 1][wad[4 + r2]] = (_Float16)hv;              \
        }                                                                      \
        if ((LASTCHK) && (TCUR) == Tt - 1) {                                   \
            _Pragma("unroll") for (int u2 = 0; u2 < 2; ++u2)                   \
                _Pragma("unroll") for (int r2 = 0; r2 < 4; ++r2) {             \
                    const floatx4 a2 = (u2 == 0) ? acc0 : acc1;                \
                    hfin[(16 * g + 4 * q + r2) * Hh + 32 * w + 16 * u2 + m] =  \
                        fast_tanh(a2[r2]);                                     \
                }                                                              \
        }                                                                      \
        yst += Hh * 4;                                                         \
        LDS_BARRIER();                                                         \
    }

    for (int t = 0; t < Tt; t += 2) {
        RNN_STEP(0, pxA, pxB, 0, t)
        RNN_STEP(1, pxB, pxA, 1, t + 1)
    }
#undef RNN_STEP
}

extern "C" void kernel_launch(void* const* d_in, const int* in_sizes, int n_in,
                              void* d_out, int out_size, void* d_ws, size_t ws_size,
                              hipStream_t stream) {
    const float* c0  = (const float*)d_in[0];  // [B,H]
    const float* xs  = (const float*)d_in[1];  // [B,T,D]
    const float* Wih = (const float*)d_in[2];  // [D,H]
    const float* Whh = (const float*)d_in[3];  // [H,H]
    const float* bhh = (const float*)d_in[4];  // [H]
    float* out = (float*)d_out;
    float* hfin = out;                 // [B,H]
    float* ys = out + Bb * Hh;         // [B,T,H] — also holds px between kernels

    // 1024 blocks * 8 tiles * 16 rows = 131072 = B*T rows.
    px_gemm<<<1024, 256, 0, stream>>>(xs, Wih, bhh, ys);
    // 4 blocks * 16 rows = 64 batch chains.
    rnn_scan<<<Bb / 16, 512, 0, stream>>>(c0, Whh, hfin, ys);
}